// Round 13
// baseline (433.907 us; speedup 1.0000x reference)
//
#include <hip/hip_runtime.h>

#define IMH 512
#define IMW 512
#define NB 4
#define NPIX (IMH*IMW)

#define TX 64
#define TY 32
#define GXT 8                 // IMW/TX
#define GYT 16                // IMH/TY
#define NBLK (GXT*GYT*NB)     // 512  == 2 blocks/CU exactly
#define NTH 1024              // 16 waves/block -> 32 waves/CU (max occupancy)

// k=4 fusion; in-place LDS p; per-thread REGISTER cache of own-cell state:
//   preg1/preg2 = own p chunk, vreg = own v, freg = own f, greg = own ginv
//   (computed in-dispatch from f, no init kernel), rreg = forwarded own r.
// Staging dedupe: interior of P LDS written from preg registers; only the
// 140-chunk outer ring loaded from global (1 round).
// Ownership frame: rows [-8,40) x chunks [-8,72) -> 48x20 = 960 threads.
// P (p): y [-9,41) 50 rows, x [-12,76) stride 88
// R (r): y [-8,40) 48 rows, x [-8,72)  stride 80
// LDS = (50*88*2 + 48*80)*4 = 50,560 B -> 2 blocks/CU.
#define PW2 88
#define P_H2 50
#define VW2 80
#define V_H2 48

#define PIDX(y,x) (((y)+9)*PW2 + ((x)+12))
#define VIDX(y,x) (((y)+8)*VW2 + ((x)+8))

__device__ __forceinline__ float4 lds4(const float* p, int i){ return *(const float4*)(p + i); }
__device__ __forceinline__ void  sts4(float* p, int i, float4 v){ *(float4*)(p + i) = v; }
__device__ __forceinline__ float4 f4zero(){ return make_float4(0.f,0.f,0.f,0.f); }
__device__ __forceinline__ float shrink01(float d){
  return d - fminf(fmaxf(d, -0.1f), 0.1f);   // v_med3 idiom
}

template<bool EDGE>
__device__ __forceinline__ float4 gld4(const float* base, int gy, int gx){
  if (EDGE){ gy = min(max(gy,0),IMH-1); gx = min(max(gx,0),IMW-4); }
  return *(const float4*)(base + gy*IMW + gx);
}
__device__ __forceinline__ float4 mask4(float4 v, int gy, int gx){
  if ((unsigned)gy >= (unsigned)IMH) return f4zero();
  v.x = ((unsigned)(gx+0) < (unsigned)IMW) ? v.x : 0.f;
  v.y = ((unsigned)(gx+1) < (unsigned)IMW) ? v.y : 0.f;
  v.z = ((unsigned)(gx+2) < (unsigned)IMW) ? v.z : 0.f;
  v.w = ((unsigned)(gx+3) < (unsigned)IMW) ? v.w : 0.f;
  return v;
}

// row window: only lw (x-1) and rx (x+4) cross the chunk
struct RowS { float lw; float4 m; float rx; };
__device__ __forceinline__ RowS load_rowS(const float* A, int base, int lo, int ro){
  RowS q; q.m = lds4(A, base); q.lw = A[base+lo]; q.rx = A[base+ro]; return q;
}
__device__ __forceinline__ float4 dxvS(const RowS& q){
  return make_float4(q.m.y - q.lw, q.m.z - q.m.x, q.m.w - q.m.y, q.rx - q.m.z);
}
__device__ __forceinline__ void sobel_rowsS(const RowS& A, const RowS& B, const RowS& C,
                                            float4& rgx, float4& rgy){
  float4 da = dxvS(A), db = dxvS(B), dc = dxvS(C);
  rgx.x = (da.x + 2.f*db.x + dc.x) * 0.125f;
  rgx.y = (da.y + 2.f*db.y + dc.y) * 0.125f;
  rgx.z = (da.z + 2.f*db.z + dc.z) * 0.125f;
  rgx.w = (da.w + 2.f*db.w + dc.w) * 0.125f;
  float cm1 = C.lw - A.lw;
  float c0 = C.m.x - A.m.x, c1 = C.m.y - A.m.y;
  float c2 = C.m.z - A.m.z, c3 = C.m.w - A.m.w;
  float c4 = C.rx - A.rx;
  rgy.x = (cm1 + 2.f*c0 + c1) * 0.125f;
  rgy.y = (c0  + 2.f*c1 + c2) * 0.125f;
  rgy.z = (c1  + 2.f*c2 + c3) * 0.125f;
  rgy.w = (c2  + 2.f*c3 + c4) * 0.125f;
}
__device__ __forceinline__ void p_elem(float4 rgx, float4 rgy, float4 pa, float4 pb,
                                       float4 gg, float4& n1, float4& n2){
#define PE(c) { \
    float mag = __builtin_amdgcn_sqrtf(rgx.c*rgx.c + rgy.c*rgy.c); \
    float inv = __builtin_amdgcn_rcpf(1.f + 0.125f*mag*gg.c); \
    n1.c = (pa.c + 0.125f*rgx.c)*inv; n2.c = (pb.c + 0.125f*rgy.c)*inv; }
  PE(x) PE(y) PE(z) PE(w)
#undef PE
}

// div(p) at own cell: m from register, neighbors from LDS
__device__ __forceinline__ float4 divp_reg(const float* P1s, const float* P2s,
                                           int pc, float4 m){
  float lw = P1s[pc-1], rx = P1s[pc+4];
  float4 up = lds4(P2s,pc-PW2), dn = lds4(P2s,pc+PW2);
  float4 db;
  db.x = (m.y - lw)  + (dn.x - up.x);
  db.y = (m.z - m.x) + (dn.y - up.y);
  db.z = (m.w - m.y) + (dn.z - up.z);
  db.w = (rx  - m.z) + (dn.w - up.w);
  return db;
}

// p-update at own cell; own-row R m comes from rreg (forwarded), neighbors LDS
template<bool EDGE>
__device__ __forceinline__ void p_phase(const float* Rs, float* P1s, float* P2s,
    float4 greg, float4 rreg, int x0, int y0, int vy, int vx, bool vown,
    float4& preg1, float4& preg2, int ylo, int nrows){
  if (!vown) return;
  if (vy < ylo || vy >= ylo + nrows) return;
  int col = vx + 8;                     // column in R coords (stride 80)
  int lo = (col==0) ? 0 : -1;           // clamped reads feed junk cells only
  int ro = (col==76) ? 0 : 4;
  int base = VIDX(vy,vx);
  RowS Rm1 = load_rowS(Rs, base-VW2, lo, ro);
  RowS R1  = load_rowS(Rs, base+VW2, lo, ro);
  RowS R0;  R0.m = rreg; R0.lw = Rs[base+lo]; R0.rx = Rs[base+ro];
  float4 rgx, rgy;
  sobel_rowsS(Rm1, R0, R1, rgx, rgy);
  float4 n1, n2;
  p_elem(rgx,rgy,preg1,preg2,greg,n1,n2);
  if (EDGE){
    n1 = mask4(n1, y0+vy, x0+vx); n2 = mask4(n2, y0+vy, x0+vx);
  }
  preg1 = n1; preg2 = n2;
  int p0 = PIDX(vy,vx);
  sts4(P1s,p0,n1); sts4(P2s,p0,n2);
}

// v-update (register, skipped when FIRSTR) + r = div(p)-f+v -> Rs and rreg
template<bool EDGE, bool FIRSTR>
__device__ __forceinline__ void vr_phase(float* Rs, const float* P1s, const float* P2s,
    float4& vreg, float4 freg, float4 preg1, float4& rreg, int x0, int y0,
    int vy, int vx, bool vown, int ylo, int nrows){
  if (!vown) return;
  if (vy < ylo || vy >= ylo + nrows) return;
  float4 db = divp_reg(P1s, P2s, PIDX(vy,vx), preg1);
  if (!FIRSTR){
    vreg.x = shrink01(vreg.x + db.x); vreg.y = shrink01(vreg.y + db.y);
    vreg.z = shrink01(vreg.z + db.z); vreg.w = shrink01(vreg.w + db.w);
  }
  float4 rv;
  rv.x = db.x - freg.x + vreg.x; rv.y = db.y - freg.y + vreg.y;
  rv.z = db.z - freg.z + vreg.z; rv.w = db.w - freg.w + vreg.w;
  if (EDGE) rv = mask4(rv, y0+vy, x0+vx);
  rreg = rv;
  sts4(Rs, VIDX(vy,vx), rv);
}

template<bool FIRST, bool LAST, bool EDGE>
__device__ __forceinline__ void iter_body4(
    const float* fb,
    const float* p1b, const float* p2b, const float* vb,
    float* p1o, float* p2o, float* vo, float* uo,
    int x0, int y0, int tid,
    float* P1s, float* P2s, float* Rs)
{
  // fixed ownership frame: rows [-8,40) x chunks [-8,72) = 48x20 = 960
  const bool vown = tid < 960;
  const int vcy = tid / 20, vcx = tid - vcy*20;
  const int vy = vcy - 8, vx = vcx*4 - 8;

  // ---- prefetch own-cell state from global; compute greg (ginv) from f
  float4 vreg = f4zero(), preg1 = f4zero(), preg2 = f4zero();
  float4 freg = f4zero(), greg = f4zero(), rreg = f4zero();
  if (vown){
    int gy = y0+vy, gx = x0+vx;
    // three f rows (zero-padded SAME semantics), reusing sobel_rowsS
    RowS F0, F1, F2;
#define LOADFROW(D, DST) { \
      int yy = gy + (D) - 1; \
      float4 L, M, Rr; \
      if (EDGE){ \
        if ((unsigned)yy >= (unsigned)IMH){ L = f4zero(); M = f4zero(); Rr = f4zero(); } \
        else { \
          L  = mask4(gld4<true>(fb, yy, gx-4), yy, gx-4); \
          M  = mask4(gld4<true>(fb, yy, gx  ), yy, gx  ); \
          Rr = mask4(gld4<true>(fb, yy, gx+4), yy, gx+4); \
        } \
      } else { \
        const float* rp_ = fb + (size_t)yy*IMW + gx; \
        L = *(const float4*)(rp_-4); M = *(const float4*)rp_; Rr = *(const float4*)(rp_+4); \
      } \
      DST.lw = L.w; DST.m = M; DST.rx = Rr.x; }
    LOADFROW(0, F0)
    LOADFROW(1, F1)
    LOADFROW(2, F2)
#undef LOADFROW
    freg = F1.m;
    float4 sx, sy;
    sobel_rowsS(F0, F1, F2, sx, sy);   // = true sobel / 8
    greg.x = 1.f + 64.f*(sx.x*sx.x + sy.x*sy.x);
    greg.y = 1.f + 64.f*(sx.y*sx.y + sy.y*sy.y);
    greg.z = 1.f + 64.f*(sx.z*sx.z + sy.z*sy.z);
    greg.w = 1.f + 64.f*(sx.w*sx.w + sy.w*sy.w);
    if (!FIRST){
      preg1 = gld4<EDGE>(p1b, gy, gx);
      preg2 = gld4<EDGE>(p2b, gy, gx);
      vreg  = gld4<EDGE>(vb,  gy, gx);
      if (EDGE){
        preg1 = mask4(preg1, gy, gx); preg2 = mask4(preg2, gy, gx);
        vreg  = mask4(vreg,  gy, gx);
      }
    }
  }

  // ---- stage P LDS: interior from registers (no global re-read)
  if (vown){
    int idx = PIDX(vy,vx);
    sts4(P1s, idx, preg1); sts4(P2s, idx, preg2);
  }
  // ---- outer ring (P frame minus ownership frame): 140 chunks, 1 round
  if (tid < 140){
    int y, x;
    if (tid < 22){ y = -9; x = tid*4 - 12; }
    else if (tid < 44){ y = 40; x = (tid-22)*4 - 12; }
    else { int k = tid - 44; y = (k >> 1) - 8; x = (k & 1) ? 72 : -12; }
    float4 a, b;
    if (FIRST){ a = f4zero(); b = f4zero(); }
    else {
      int gy = y0+y, gx = x0+x;
      a = gld4<EDGE>(p1b, gy, gx); b = gld4<EDGE>(p2b, gy, gx);
      if (EDGE){ a = mask4(a,gy,gx); b = mask4(b,gy,gx); }
    }
    int idx = PIDX(y,x);
    sts4(P1s, idx, a); sts4(P2s, idx, b);
  }
  __syncthreads();

  // ---- 4 fused iterations, halo ladder 8->1
  vr_phase<EDGE,true >(Rs,P1s,P2s,vreg,freg,preg1,rreg,x0,y0,vy,vx,vown,-8,48); __syncthreads();
  p_phase<EDGE>(Rs,P1s,P2s,greg,rreg,x0,y0,vy,vx,vown,preg1,preg2,-7,46);       __syncthreads();
  vr_phase<EDGE,false>(Rs,P1s,P2s,vreg,freg,preg1,rreg,x0,y0,vy,vx,vown,-6,44); __syncthreads();
  p_phase<EDGE>(Rs,P1s,P2s,greg,rreg,x0,y0,vy,vx,vown,preg1,preg2,-5,42);       __syncthreads();
  vr_phase<EDGE,false>(Rs,P1s,P2s,vreg,freg,preg1,rreg,x0,y0,vy,vx,vown,-4,40); __syncthreads();
  p_phase<EDGE>(Rs,P1s,P2s,greg,rreg,x0,y0,vy,vx,vown,preg1,preg2,-3,38);       __syncthreads();
  vr_phase<EDGE,false>(Rs,P1s,P2s,vreg,freg,preg1,rreg,x0,y0,vy,vx,vown,-2,36); __syncthreads();
  p_phase<EDGE>(Rs,P1s,P2s,greg,rreg,x0,y0,vy,vx,vown,preg1,preg2,-1,34);       __syncthreads();

  // ---- outputs over owned tile: everything own-cell is in registers
  if (vown && vy >= 0 && vy < TY && vx >= 0 && vx < TX){
    float4 dq = divp_reg(P1s, P2s, PIDX(vy,vx), preg1);
    size_t go = (size_t)(y0+vy)*IMW + (x0+vx);
    if (LAST){
      float4 uu;
      uu.x = freg.x - vreg.x - dq.x; uu.y = freg.y - vreg.y - dq.y;
      uu.z = freg.z - vreg.z - dq.z; uu.w = freg.w - vreg.w - dq.w;
      *(float4*)(uo + go) = uu;
    } else {
      float4 vn;
      vn.x = shrink01(vreg.x + dq.x); vn.y = shrink01(vreg.y + dq.y);
      vn.z = shrink01(vreg.z + dq.z); vn.w = shrink01(vreg.w + dq.w);
      *(float4*)(p1o + go) = preg1;
      *(float4*)(p2o + go) = preg2;
      *(float4*)(vo  + go) = vn;
    }
  }
}

template<bool FIRST, bool LAST>
__global__ __launch_bounds__(NTH, 8) void iter4_kernel(
    const float* __restrict__ f,
    const float* __restrict__ p1in, const float* __restrict__ p2in,
    const float* __restrict__ vin,
    float* __restrict__ p1out, float* __restrict__ p2out,
    float* __restrict__ vout, float* __restrict__ uout)
{
  __shared__ alignas(16) float P1s[P_H2*PW2], P2s[P_H2*PW2];
  __shared__ alignas(16) float Rs[V_H2*VW2];

  int phys = blockIdx.x;
  int virt = (phys & 7) * (NBLK/8) + (phys >> 3);   // XCD-chunked, bijective
  int bx = virt & (GXT-1);
  int by = (virt >> 3) & (GYT-1);
  int b  = virt >> 7;
  int x0 = bx*TX, y0 = by*TY;
  size_t boff = (size_t)b * NPIX;
  bool edge = (bx==0) | (bx==GXT-1) | (by==0) | (by==GYT-1);
  int tid = threadIdx.x;

  if (edge)
    iter_body4<FIRST,LAST,true>(f+boff, p1in+boff, p2in+boff, vin+boff,
        p1out+boff, p2out+boff, vout+boff, uout+boff, x0, y0, tid,
        P1s, P2s, Rs);
  else
    iter_body4<FIRST,LAST,false>(f+boff, p1in+boff, p2in+boff, vin+boff,
        p1out+boff, p2out+boff, vout+boff, uout+boff, x0, y0, tid,
        P1s, P2s, Rs);
}

extern "C" void kernel_launch(void* const* d_in, const int* in_sizes, int n_in,
                              void* d_out, int out_size, void* d_ws, size_t ws_size,
                              hipStream_t stream) {
  const float* f = (const float*)d_in[0];
  float* u = (float*)d_out;
  float* ws = (float*)d_ws;
  const size_t N = (size_t)NB * NPIX;
  float* p1a = ws + 0*N;
  float* p2a = ws + 1*N;
  float* va  = ws + 2*N;
  float* p1b = ws + 3*N;
  float* p2b = ws + 4*N;
  float* vb  = ws + 5*N;

  for (int l = 0; l < 25; ++l) {   // 25 x 4 fused = 100 iterations
    const float *pi1, *pi2, *vi;
    float *po1, *po2, *vo;
    if (l & 1) { pi1 = p1b; pi2 = p2b; vi = vb; po1 = p1a; po2 = p2a; vo = va; }
    else       { pi1 = p1a; pi2 = p2a; vi = va; po1 = p1b; po2 = p2b; vo = vb; }
    if (l == 0)
      iter4_kernel<true, false><<<NBLK, NTH, 0, stream>>>(f, pi1, pi2, vi, po1, po2, vo, u);
    else if (l == 24)
      iter4_kernel<false, true><<<NBLK, NTH, 0, stream>>>(f, pi1, pi2, vi, po1, po2, vo, u);
    else
      iter4_kernel<false, false><<<NBLK, NTH, 0, stream>>>(f, pi1, pi2, vi, po1, po2, vo, u);
  }
}

// Round 14
// 370.714 us; speedup vs baseline: 1.1705x; 1.1705x over previous
//
#include <hip/hip_runtime.h>

#define IMH 512
#define IMW 512
#define NB 4
#define NPIX (IMH*IMW)

#define TX 64
#define TY 32
#define GXT 8                 // IMW/TX
#define GYT 16                // IMH/TY
#define NBLK (GXT*GYT*NB)     // 512  == 2 blocks/CU exactly
#define NTH 1024              // 16 waves/block -> 32 waves/CU (max occupancy)

// k=4 fusion; in-place LDS p; per-thread REGISTER cache of own-cell state:
//   preg1/preg2 = own p chunk, vreg = own v, freg = own f, greg = own ginv,
//   rreg = own r (forwarded vr_phase -> p_phase).
// ginv computed once in dispatch 0's prologue (written to ws), read by later
// dispatches (R11 structure, init kernel folded into FIRST).
// Staging dedupe: interior of P LDS written from preg registers; only the
// 140-chunk outer ring loaded from global (1 round).
// Ownership frame: rows [-8,40) x chunks [-8,72) -> 48x20 = 960 threads.
// P (p): y [-9,41) 50 rows, x [-12,76) stride 88
// R (r): y [-8,40) 48 rows, x [-8,72)  stride 80
// LDS = (50*88*2 + 48*80)*4 = 50,560 B -> 2 blocks/CU.
#define PW2 88
#define P_H2 50
#define VW2 80
#define V_H2 48

#define PIDX(y,x) (((y)+9)*PW2 + ((x)+12))
#define VIDX(y,x) (((y)+8)*VW2 + ((x)+8))

__device__ __forceinline__ float4 lds4(const float* p, int i){ return *(const float4*)(p + i); }
__device__ __forceinline__ void  sts4(float* p, int i, float4 v){ *(float4*)(p + i) = v; }
__device__ __forceinline__ float4 f4zero(){ return make_float4(0.f,0.f,0.f,0.f); }
__device__ __forceinline__ float shrink01(float d){
  return d - fminf(fmaxf(d, -0.1f), 0.1f);   // v_med3 idiom
}

template<bool EDGE>
__device__ __forceinline__ float4 gld4(const float* base, int gy, int gx){
  if (EDGE){ gy = min(max(gy,0),IMH-1); gx = min(max(gx,0),IMW-4); }
  return *(const float4*)(base + gy*IMW + gx);
}
__device__ __forceinline__ float4 mask4(float4 v, int gy, int gx){
  if ((unsigned)gy >= (unsigned)IMH) return f4zero();
  v.x = ((unsigned)(gx+0) < (unsigned)IMW) ? v.x : 0.f;
  v.y = ((unsigned)(gx+1) < (unsigned)IMW) ? v.y : 0.f;
  v.z = ((unsigned)(gx+2) < (unsigned)IMW) ? v.z : 0.f;
  v.w = ((unsigned)(gx+3) < (unsigned)IMW) ? v.w : 0.f;
  return v;
}

// row window: only lw (x-1) and rx (x+4) cross the chunk
struct RowS { float lw; float4 m; float rx; };
__device__ __forceinline__ RowS load_rowS(const float* A, int base, int lo, int ro){
  RowS q; q.m = lds4(A, base); q.lw = A[base+lo]; q.rx = A[base+ro]; return q;
}
__device__ __forceinline__ float4 dxvS(const RowS& q){
  return make_float4(q.m.y - q.lw, q.m.z - q.m.x, q.m.w - q.m.y, q.rx - q.m.z);
}
__device__ __forceinline__ void sobel_rowsS(const RowS& A, const RowS& B, const RowS& C,
                                            float4& rgx, float4& rgy){
  float4 da = dxvS(A), db = dxvS(B), dc = dxvS(C);
  rgx.x = (da.x + 2.f*db.x + dc.x) * 0.125f;
  rgx.y = (da.y + 2.f*db.y + dc.y) * 0.125f;
  rgx.z = (da.z + 2.f*db.z + dc.z) * 0.125f;
  rgx.w = (da.w + 2.f*db.w + dc.w) * 0.125f;
  float cm1 = C.lw - A.lw;
  float c0 = C.m.x - A.m.x, c1 = C.m.y - A.m.y;
  float c2 = C.m.z - A.m.z, c3 = C.m.w - A.m.w;
  float c4 = C.rx - A.rx;
  rgy.x = (cm1 + 2.f*c0 + c1) * 0.125f;
  rgy.y = (c0  + 2.f*c1 + c2) * 0.125f;
  rgy.z = (c1  + 2.f*c2 + c3) * 0.125f;
  rgy.w = (c2  + 2.f*c3 + c4) * 0.125f;
}
__device__ __forceinline__ void p_elem(float4 rgx, float4 rgy, float4 pa, float4 pb,
                                       float4 gg, float4& n1, float4& n2){
#define PE(c) { \
    float mag = __builtin_amdgcn_sqrtf(rgx.c*rgx.c + rgy.c*rgy.c); \
    float inv = __builtin_amdgcn_rcpf(1.f + 0.125f*mag*gg.c); \
    n1.c = (pa.c + 0.125f*rgx.c)*inv; n2.c = (pb.c + 0.125f*rgy.c)*inv; }
  PE(x) PE(y) PE(z) PE(w)
#undef PE
}

// div(p) at own cell: m from register, neighbors from LDS
__device__ __forceinline__ float4 divp_reg(const float* P1s, const float* P2s,
                                           int pc, float4 m){
  float lw = P1s[pc-1], rx = P1s[pc+4];
  float4 up = lds4(P2s,pc-PW2), dn = lds4(P2s,pc+PW2);
  float4 db;
  db.x = (m.y - lw)  + (dn.x - up.x);
  db.y = (m.z - m.x) + (dn.y - up.y);
  db.z = (m.w - m.y) + (dn.z - up.z);
  db.w = (rx  - m.z) + (dn.w - up.w);
  return db;
}

// p-update at own cell; own-row R m comes from rreg (forwarded), neighbors LDS
template<bool EDGE>
__device__ __forceinline__ void p_phase(const float* Rs, float* P1s, float* P2s,
    float4 greg, float4 rreg, int x0, int y0, int vy, int vx, bool vown,
    float4& preg1, float4& preg2, int ylo, int nrows){
  if (!vown) return;
  if (vy < ylo || vy >= ylo + nrows) return;
  int col = vx + 8;                     // column in R coords (stride 80)
  int lo = (col==0) ? 0 : -1;           // clamped reads feed junk cells only
  int ro = (col==76) ? 0 : 4;
  int base = VIDX(vy,vx);
  RowS Rm1 = load_rowS(Rs, base-VW2, lo, ro);
  RowS R1  = load_rowS(Rs, base+VW2, lo, ro);
  RowS R0;  R0.m = rreg; R0.lw = Rs[base+lo]; R0.rx = Rs[base+ro];
  float4 rgx, rgy;
  sobel_rowsS(Rm1, R0, R1, rgx, rgy);
  float4 n1, n2;
  p_elem(rgx,rgy,preg1,preg2,greg,n1,n2);
  if (EDGE){
    n1 = mask4(n1, y0+vy, x0+vx); n2 = mask4(n2, y0+vy, x0+vx);
  }
  preg1 = n1; preg2 = n2;
  int p0 = PIDX(vy,vx);
  sts4(P1s,p0,n1); sts4(P2s,p0,n2);
}

// v-update (register, skipped when FIRSTR) + r = div(p)-f+v -> Rs and rreg
template<bool EDGE, bool FIRSTR>
__device__ __forceinline__ void vr_phase(float* Rs, const float* P1s, const float* P2s,
    float4& vreg, float4 freg, float4 preg1, float4& rreg, int x0, int y0,
    int vy, int vx, bool vown, int ylo, int nrows){
  if (!vown) return;
  if (vy < ylo || vy >= ylo + nrows) return;
  float4 db = divp_reg(P1s, P2s, PIDX(vy,vx), preg1);
  if (!FIRSTR){
    vreg.x = shrink01(vreg.x + db.x); vreg.y = shrink01(vreg.y + db.y);
    vreg.z = shrink01(vreg.z + db.z); vreg.w = shrink01(vreg.w + db.w);
  }
  float4 rv;
  rv.x = db.x - freg.x + vreg.x; rv.y = db.y - freg.y + vreg.y;
  rv.z = db.z - freg.z + vreg.z; rv.w = db.w - freg.w + vreg.w;
  if (EDGE) rv = mask4(rv, y0+vy, x0+vx);
  rreg = rv;
  sts4(Rs, VIDX(vy,vx), rv);
}

template<bool FIRST, bool LAST, bool EDGE>
__device__ __forceinline__ void iter_body4(
    const float* fb, const float* gb, float* gwr,
    const float* p1b, const float* p2b, const float* vb,
    float* p1o, float* p2o, float* vo, float* uo,
    int x0, int y0, int tid,
    float* P1s, float* P2s, float* Rs)
{
  // fixed ownership frame: rows [-8,40) x chunks [-8,72) = 48x20 = 960
  const bool vown = tid < 960;
  const int vcy = tid / 20, vcx = tid - vcy*20;
  const int vy = vcy - 8, vx = vcx*4 - 8;

  // ---- prefetch own-cell state from global
  float4 vreg = f4zero(), preg1 = f4zero(), preg2 = f4zero();
  float4 freg = f4zero(), greg = f4zero(), rreg = f4zero();
  if (vown){
    int gy = y0+vy, gx = x0+vx;
    if (FIRST){
      // compute ginv = 1 + gx^2 + gy^2 from f (zero-padded), publish to ws
      RowS F0, F1, F2;
#define LOADFROW(D, DST) { \
      int yy = gy + (D) - 1; \
      float4 L, M, Rr; \
      if (EDGE){ \
        if ((unsigned)yy >= (unsigned)IMH){ L = f4zero(); M = f4zero(); Rr = f4zero(); } \
        else { \
          L  = mask4(gld4<true>(fb, yy, gx-4), yy, gx-4); \
          M  = mask4(gld4<true>(fb, yy, gx  ), yy, gx  ); \
          Rr = mask4(gld4<true>(fb, yy, gx+4), yy, gx+4); \
        } \
      } else { \
        const float* rp_ = fb + (size_t)yy*IMW + gx; \
        L = *(const float4*)(rp_-4); M = *(const float4*)rp_; Rr = *(const float4*)(rp_+4); \
      } \
      DST.lw = L.w; DST.m = M; DST.rx = Rr.x; }
      LOADFROW(0, F0)
      LOADFROW(1, F1)
      LOADFROW(2, F2)
#undef LOADFROW
      freg = F1.m;
      float4 sx, sy;
      sobel_rowsS(F0, F1, F2, sx, sy);   // = true sobel / 8
      greg.x = 1.f + 64.f*(sx.x*sx.x + sy.x*sy.x);
      greg.y = 1.f + 64.f*(sx.y*sx.y + sy.y*sy.y);
      greg.z = 1.f + 64.f*(sx.z*sx.z + sy.z*sy.z);
      greg.w = 1.f + 64.f*(sx.w*sx.w + sy.w*sy.w);
      if ((unsigned)gy < (unsigned)IMH && (unsigned)gx < (unsigned)IMW)
        *(float4*)(gwr + (size_t)gy*IMW + gx) = greg;   // benign identical-value overlap
    } else {
      freg = gld4<EDGE>(fb, gy, gx);
      greg = gld4<EDGE>(gb, gy, gx);
      preg1 = gld4<EDGE>(p1b, gy, gx);
      preg2 = gld4<EDGE>(p2b, gy, gx);
      vreg  = gld4<EDGE>(vb,  gy, gx);
      if (EDGE){
        preg1 = mask4(preg1, gy, gx); preg2 = mask4(preg2, gy, gx);
        vreg  = mask4(vreg,  gy, gx);
      }
    }
  }

  // ---- stage P LDS: interior from registers (no global re-read)
  if (vown){
    int idx = PIDX(vy,vx);
    sts4(P1s, idx, preg1); sts4(P2s, idx, preg2);
  }
  // ---- outer ring (P frame minus ownership frame): 140 chunks, 1 round
  if (tid < 140){
    int y, x;
    if (tid < 22){ y = -9; x = tid*4 - 12; }
    else if (tid < 44){ y = 40; x = (tid-22)*4 - 12; }
    else { int k = tid - 44; y = (k >> 1) - 8; x = (k & 1) ? 72 : -12; }
    float4 a, b;
    if (FIRST){ a = f4zero(); b = f4zero(); }
    else {
      int gy = y0+y, gx = x0+x;
      a = gld4<EDGE>(p1b, gy, gx); b = gld4<EDGE>(p2b, gy, gx);
      if (EDGE){ a = mask4(a,gy,gx); b = mask4(b,gy,gx); }
    }
    int idx = PIDX(y,x);
    sts4(P1s, idx, a); sts4(P2s, idx, b);
  }
  __syncthreads();

  // ---- 4 fused iterations, halo ladder 8->1
  vr_phase<EDGE,true >(Rs,P1s,P2s,vreg,freg,preg1,rreg,x0,y0,vy,vx,vown,-8,48); __syncthreads();
  p_phase<EDGE>(Rs,P1s,P2s,greg,rreg,x0,y0,vy,vx,vown,preg1,preg2,-7,46);       __syncthreads();
  vr_phase<EDGE,false>(Rs,P1s,P2s,vreg,freg,preg1,rreg,x0,y0,vy,vx,vown,-6,44); __syncthreads();
  p_phase<EDGE>(Rs,P1s,P2s,greg,rreg,x0,y0,vy,vx,vown,preg1,preg2,-5,42);       __syncthreads();
  vr_phase<EDGE,false>(Rs,P1s,P2s,vreg,freg,preg1,rreg,x0,y0,vy,vx,vown,-4,40); __syncthreads();
  p_phase<EDGE>(Rs,P1s,P2s,greg,rreg,x0,y0,vy,vx,vown,preg1,preg2,-3,38);       __syncthreads();
  vr_phase<EDGE,false>(Rs,P1s,P2s,vreg,freg,preg1,rreg,x0,y0,vy,vx,vown,-2,36); __syncthreads();
  p_phase<EDGE>(Rs,P1s,P2s,greg,rreg,x0,y0,vy,vx,vown,preg1,preg2,-1,34);       __syncthreads();

  // ---- outputs over owned tile: everything own-cell is in registers
  if (vown && vy >= 0 && vy < TY && vx >= 0 && vx < TX){
    float4 dq = divp_reg(P1s, P2s, PIDX(vy,vx), preg1);
    size_t go = (size_t)(y0+vy)*IMW + (x0+vx);
    if (LAST){
      float4 uu;
      uu.x = freg.x - vreg.x - dq.x; uu.y = freg.y - vreg.y - dq.y;
      uu.z = freg.z - vreg.z - dq.z; uu.w = freg.w - vreg.w - dq.w;
      *(float4*)(uo + go) = uu;
    } else {
      float4 vn;
      vn.x = shrink01(vreg.x + dq.x); vn.y = shrink01(vreg.y + dq.y);
      vn.z = shrink01(vreg.z + dq.z); vn.w = shrink01(vreg.w + dq.w);
      *(float4*)(p1o + go) = preg1;
      *(float4*)(p2o + go) = preg2;
      *(float4*)(vo  + go) = vn;
    }
  }
}

template<bool FIRST, bool LAST>
__global__ __launch_bounds__(NTH, 8) void iter4_kernel(
    const float* __restrict__ f, const float* __restrict__ ginv, float* gwr,
    const float* __restrict__ p1in, const float* __restrict__ p2in,
    const float* __restrict__ vin,
    float* __restrict__ p1out, float* __restrict__ p2out,
    float* __restrict__ vout, float* __restrict__ uout)
{
  __shared__ alignas(16) float P1s[P_H2*PW2], P2s[P_H2*PW2];
  __shared__ alignas(16) float Rs[V_H2*VW2];

  int phys = blockIdx.x;
  int virt = (phys & 7) * (NBLK/8) + (phys >> 3);   // XCD-chunked, bijective
  int bx = virt & (GXT-1);
  int by = (virt >> 3) & (GYT-1);
  int b  = virt >> 7;
  int x0 = bx*TX, y0 = by*TY;
  size_t boff = (size_t)b * NPIX;
  bool edge = (bx==0) | (bx==GXT-1) | (by==0) | (by==GYT-1);
  int tid = threadIdx.x;

  if (edge)
    iter_body4<FIRST,LAST,true>(f+boff, ginv+boff, gwr+boff,
        p1in+boff, p2in+boff, vin+boff,
        p1out+boff, p2out+boff, vout+boff, uout+boff, x0, y0, tid,
        P1s, P2s, Rs);
  else
    iter_body4<FIRST,LAST,false>(f+boff, ginv+boff, gwr+boff,
        p1in+boff, p2in+boff, vin+boff,
        p1out+boff, p2out+boff, vout+boff, uout+boff, x0, y0, tid,
        P1s, P2s, Rs);
}

extern "C" void kernel_launch(void* const* d_in, const int* in_sizes, int n_in,
                              void* d_out, int out_size, void* d_ws, size_t ws_size,
                              hipStream_t stream) {
  const float* f = (const float*)d_in[0];
  float* u = (float*)d_out;
  float* ws = (float*)d_ws;
  const size_t N = (size_t)NB * NPIX;
  float* g   = ws + 0*N;
  float* p1a = ws + 1*N;
  float* p2a = ws + 2*N;
  float* va  = ws + 3*N;
  float* p1b = ws + 4*N;
  float* p2b = ws + 5*N;
  float* vb  = ws + 6*N;

  for (int l = 0; l < 25; ++l) {   // 25 x 4 fused = 100 iterations
    const float *pi1, *pi2, *vi;
    float *po1, *po2, *vo;
    if (l & 1) { pi1 = p1b; pi2 = p2b; vi = vb; po1 = p1a; po2 = p2a; vo = va; }
    else       { pi1 = p1a; pi2 = p2a; vi = va; po1 = p1b; po2 = p2b; vo = vb; }
    if (l == 0)
      iter4_kernel<true, false><<<NBLK, NTH, 0, stream>>>(f, g, g, pi1, pi2, vi, po1, po2, vo, u);
    else if (l == 24)
      iter4_kernel<false, true><<<NBLK, NTH, 0, stream>>>(f, g, g, pi1, pi2, vi, po1, po2, vo, u);
    else
      iter4_kernel<false, false><<<NBLK, NTH, 0, stream>>>(f, g, g, pi1, pi2, vi, po1, po2, vo, u);
  }
}